// Round 1
// baseline (1835.495 us; speedup 1.0000x reference)
//
#include <hip/hip_runtime.h>
#include <hip/hip_bf16.h>

// ---------------------------------------------------------------------------
// Fused attention module: Q/K/V proj (bf16 MFMA) + RoPE + causal flash attn
// (bf16 MFMA, fp32 softmax) + output proj (fp32 out).
// MI355X / gfx950. All heavy math via mfma_f32_16x16x32_bf16.
// Verified layouts (learn_hip m89/m91/m120):
//   A-frag: A[m=lane&15][k=(lane>>4)*8+j]
//   B-frag: B[k=(lane>>4)*8+j][n=lane&15]
//   C/D   : col=lane&15, row=(lane>>4)*4+reg
// ---------------------------------------------------------------------------

typedef __bf16 bf16x8 __attribute__((ext_vector_type(8)));
typedef __bf16 bf16x4 __attribute__((ext_vector_type(4)));
typedef float  f32x4  __attribute__((ext_vector_type(4)));

#define GLD_A1(p) ((__attribute__((address_space(1))) void*)(p))
#define GLD_A3(p) ((__attribute__((address_space(3))) void*)(p))

static constexpr int   BATCH = 2;
static constexpr int   TSEQ  = 2048;
static constexpr int   DM    = 4096;
static constexpr int   NH    = 32;
static constexpr int   DH    = 128;
static constexpr size_t TS   = (size_t)DM * DM;   // 16,777,216 elems (== B*T*DM too)

// ---------------------------------------------------------------------------
// fp32 -> bf16 cast, 4 elems/thread
// ---------------------------------------------------------------------------
__global__ __launch_bounds__(256) void cast_f32_bf16(const float* __restrict__ in,
                                                     __bf16* __restrict__ out) {
    size_t id = (size_t)blockIdx.x * blockDim.x + threadIdx.x;
    float4 v = ((const float4*)in)[id];
    bf16x4 o = { (__bf16)v.x, (__bf16)v.y, (__bf16)v.z, (__bf16)v.w };
    *(bf16x4*)(out + id * 4) = o;
}

// ---------------------------------------------------------------------------
// NT GEMM: C[m][n] = sum_k A[m][k] * W[n][k];  M=N=K=4096.
// m97 structure: 128x128 tile, BK=32, 256 thr (4 waves), global_load_lds w=16.
// ---------------------------------------------------------------------------
template <bool OUT_F32>
__global__ __launch_bounds__(256) void gemm_nt(const __bf16* __restrict__ A,
                                               const __bf16* __restrict__ W,
                                               void* __restrict__ Cout) {
    constexpr int Kd = 4096, Nd = 4096;
    __shared__ alignas(16) __bf16 As[128 * 32];
    __shared__ alignas(16) __bf16 Bs[128 * 32];

    const int t = threadIdx.x, w = t >> 6, L = t & 63;
    const int lane15 = L & 15, quad = L >> 4;
    const int rowBlock = blockIdx.y * 128, colBlock = blockIdx.x * 128;
    const int wr = (w >> 1) * 64, wc = (w & 1) * 64;

    f32x4 acc[4][4] = {};

    for (int kb = 0; kb < Kd; kb += 32) {
        __syncthreads();  // prior-iter LDS reads done
#pragma unroll
        for (int i = 0; i < 2; i++) {
            const int chunk = w * 128 + i * 64 + L;     // 0..511, 16B each
            const int row = chunk >> 2, c8 = (chunk & 3) * 8;
            __builtin_amdgcn_global_load_lds(
                GLD_A1(A + (size_t)(rowBlock + row) * Kd + kb + c8),
                GLD_A3(As + (size_t)(w * 128 + i * 64) * 8), 16, 0, 0);
            __builtin_amdgcn_global_load_lds(
                GLD_A1(W + (size_t)(colBlock + row) * Kd + kb + c8),
                GLD_A3(Bs + (size_t)(w * 128 + i * 64) * 8), 16, 0, 0);
        }
        __syncthreads();  // drains vmcnt -> LDS populated

        bf16x8 a[4], b[4];
#pragma unroll
        for (int i = 0; i < 4; i++)
            a[i] = *(const bf16x8*)(As + (wr + i * 16 + lane15) * 32 + quad * 8);
#pragma unroll
        for (int j = 0; j < 4; j++)
            b[j] = *(const bf16x8*)(Bs + (wc + j * 16 + lane15) * 32 + quad * 8);
#pragma unroll
        for (int i = 0; i < 4; i++)
#pragma unroll
            for (int j = 0; j < 4; j++)
                acc[i][j] = __builtin_amdgcn_mfma_f32_16x16x32_bf16(a[i], b[j], acc[i][j], 0, 0, 0);
    }

#pragma unroll
    for (int i = 0; i < 4; i++)
#pragma unroll
        for (int j = 0; j < 4; j++)
#pragma unroll
            for (int r = 0; r < 4; r++) {
                const size_t gm = rowBlock + wr + i * 16 + quad * 4 + r;
                const size_t gn = colBlock + wc + j * 16 + lane15;
                if (OUT_F32)
                    ((float*)Cout)[gm * Nd + gn] = acc[i][j][r];
                else
                    ((__bf16*)Cout)[gm * Nd + gn] = (__bf16)acc[i][j][r];
            }
}

// ---------------------------------------------------------------------------
// RoPE in place on (B*T, 4096) bf16. Pair p of head rotates by
// angle = t * theta^(-((2p)%64)/64), theta=20000.
// ---------------------------------------------------------------------------
__global__ __launch_bounds__(256) void rope_inplace(__bf16* __restrict__ X) {
    const size_t id = (size_t)blockIdx.x * blockDim.x + threadIdx.x;  // one per pair
    const int pcol = (int)(id & 2047);      // pair within row (4096/2)
    const size_t row = id >> 11;            // 0..4095
    const int tpos = (int)(row & (TSEQ - 1));
    const int j = (2 * (pcol & 63)) & 63;   // freq index
    // log2(20000) = 14.287712379549449
    const float inv = exp2f(-(float)j * (14.287712379549449f / 64.0f));
    const float ang = (float)tpos * inv;
    float s, c;
    sincosf(ang, &s, &c);
    __bf16* p = X + row * DM + pcol * 2;
    const float x0 = (float)p[0], x1 = (float)p[1];
    p[0] = (__bf16)(x0 * c - x1 * s);
    p[1] = (__bf16)(x0 * s + x1 * c);
}

// ---------------------------------------------------------------------------
// Flash attention, causal. Q,K,V,O all (B*T, 4096) bf16 with head offset h*128.
// Block: 256 thr (4 waves). Q tile 64 rows (16/wave), K/V tiles of 64 keys.
// ---------------------------------------------------------------------------
__global__ __launch_bounds__(256) void flash_attn(const __bf16* __restrict__ Qg,
                                                  const __bf16* __restrict__ Kg,
                                                  const __bf16* __restrict__ Vg,
                                                  __bf16* __restrict__ Og) {
    const int qb = blockIdx.x;           // 0..31 (q tile)
    const int bh = blockIdx.y;           // 0..63
    const int b = bh >> 5, h = bh & 31;
    const size_t base = (size_t)b * TSEQ * DM + (size_t)h * DH;
    const __bf16* Qp = Qg + base;
    const __bf16* Kp = Kg + base;
    const __bf16* Vp = Vg + base;
    __bf16*       Op = Og + base;

    __shared__ alignas(16) __bf16 Ks[64 * 136];   // [key][dim], +8 pad
    __shared__ alignas(16) __bf16 Vt[128 * 72];   // [dim][key], +8 pad
    __shared__ alignas(16) __bf16 Ps[64 * 72];    // [qrow][key], +8 pad

    const int t = threadIdx.x, w = t >> 6, L = t & 63;
    const int lane15 = L & 15, quad = L >> 4;

    // Q A-frags live in registers for the whole block (16 rows per wave).
    bf16x8 aq[4];
    {
        const int qrow = qb * 64 + w * 16 + lane15;
#pragma unroll
        for (int ks = 0; ks < 4; ++ks)
            aq[ks] = *(const bf16x8*)(Qp + (size_t)qrow * DM + ks * 32 + quad * 8);
    }

    f32x4 o[8] = {};
    float m_i[4], l_i[4];
#pragma unroll
    for (int r = 0; r < 4; r++) { m_i[r] = -1e30f; l_i[r] = 0.0f; }
    const float scale = 0.08838834764831845f;  // 1/sqrt(128)

    for (int kt = 0; kt <= qb; ++kt) {
        // ---- stage K tile and V^T tile ----
#pragma unroll
        for (int c = 0; c < 4; c++) {
            const int chunk = c * 256 + t;       // 0..1023
            const int row = chunk >> 4;          // key 0..63
            const int c8 = (chunk & 15) * 8;     // dim chunk
            const size_t gro = (size_t)(kt * 64 + row) * DM + c8;
            bf16x8 kv = *(const bf16x8*)(Kp + gro);
            *(bf16x8*)(Ks + row * 136 + c8) = kv;
            bf16x8 vv = *(const bf16x8*)(Vp + gro);
#pragma unroll
            for (int jj = 0; jj < 8; jj++) Vt[(c8 + jj) * 72 + row] = vv[jj];
        }
        __syncthreads();

        // ---- S = Q K^T (per wave: 16 rows x 64 keys) ----
        f32x4 s[4] = {};
#pragma unroll
        for (int ks = 0; ks < 4; ++ks)
#pragma unroll
            for (int n = 0; n < 4; n++) {
                bf16x8 bk = *(const bf16x8*)(Ks + (n * 16 + lane15) * 136 + ks * 32 + quad * 8);
                s[n] = __builtin_amdgcn_mfma_f32_16x16x32_bf16(aq[ks], bk, s[n], 0, 0, 0);
            }

        // ---- scale + causal mask ----
        const bool diag = (kt == qb);
#pragma unroll
        for (int n = 0; n < 4; n++) {
            const int col = kt * 64 + n * 16 + lane15;
#pragma unroll
            for (int r = 0; r < 4; r++) {
                const int rowq = qb * 64 + w * 16 + quad * 4 + r;
                float sv = s[n][r] * scale;
                if (diag && col > rowq) sv = -1e30f;
                s[n][r] = sv;
            }
        }

        // ---- online softmax ----
        float mx[4], al[4], rs[4];
#pragma unroll
        for (int r = 0; r < 4; r++)
            mx[r] = fmaxf(fmaxf(s[0][r], s[1][r]), fmaxf(s[2][r], s[3][r]));
#pragma unroll
        for (int off = 8; off >= 1; off >>= 1)
#pragma unroll
            for (int r = 0; r < 4; r++)
                mx[r] = fmaxf(mx[r], __shfl_xor(mx[r], off));
#pragma unroll
        for (int r = 0; r < 4; r++) {
            const float mn = fmaxf(m_i[r], mx[r]);
            al[r] = __expf(m_i[r] - mn);
            m_i[r] = mn;
            rs[r] = 0.0f;
        }
#pragma unroll
        for (int n = 0; n < 4; n++)
#pragma unroll
            for (int r = 0; r < 4; r++) {
                const float p = __expf(s[n][r] - m_i[r]);
                rs[r] += p;
                Ps[(w * 16 + quad * 4 + r) * 72 + n * 16 + lane15] = (__bf16)p;
            }
#pragma unroll
        for (int off = 8; off >= 1; off >>= 1)
#pragma unroll
            for (int r = 0; r < 4; r++)
                rs[r] += __shfl_xor(rs[r], off);
#pragma unroll
        for (int r = 0; r < 4; r++) l_i[r] = l_i[r] * al[r] + rs[r];
#pragma unroll
        for (int d = 0; d < 8; ++d)
#pragma unroll
            for (int r = 0; r < 4; r++) o[d][r] *= al[r];

        __syncthreads();  // P visible (C-layout -> A-layout round trip)

        // ---- O += P V ----
#pragma unroll
        for (int ks2 = 0; ks2 < 2; ++ks2) {
            bf16x8 ap = *(const bf16x8*)(Ps + (w * 16 + lane15) * 72 + ks2 * 32 + quad * 8);
#pragma unroll
            for (int d = 0; d < 8; ++d) {
                bf16x8 bv = *(const bf16x8*)(Vt + (d * 16 + lane15) * 72 + ks2 * 32 + quad * 8);
                o[d] = __builtin_amdgcn_mfma_f32_16x16x32_bf16(ap, bv, o[d], 0, 0, 0);
            }
        }
        __syncthreads();  // before next tile overwrites Ks/Vt
    }

    // ---- epilogue: O / l ----
    float inv_l[4];
#pragma unroll
    for (int r = 0; r < 4; r++) inv_l[r] = 1.0f / l_i[r];
#pragma unroll
    for (int d = 0; d < 8; ++d)
#pragma unroll
        for (int r = 0; r < 4; r++) {
            const int rowq = qb * 64 + w * 16 + quad * 4 + r;
            Op[(size_t)rowq * DM + d * 16 + lane15] = (__bf16)(o[d][r] * inv_l[r]);
        }
}

// ---------------------------------------------------------------------------
extern "C" void kernel_launch(void* const* d_in, const int* in_sizes, int n_in,
                              void* d_out, int out_size, void* d_ws, size_t ws_size,
                              hipStream_t stream) {
    const float* hs = (const float*)d_in[0];
    const float* Wq = (const float*)d_in[1];
    const float* Wk = (const float*)d_in[2];
    const float* Wv = (const float*)d_in[3];
    const float* Wo = (const float*)d_in[4];
    float* out = (float*)d_out;

    // workspace layout: 9 bf16 buffers of TS elems (~302 MB total)
    __bf16* hs_b = (__bf16*)d_ws;
    __bf16* wq_b = hs_b + TS;
    __bf16* wk_b = wq_b + TS;
    __bf16* wv_b = wk_b + TS;
    __bf16* wo_b = wv_b + TS;
    __bf16* Qb   = wo_b + TS;
    __bf16* Kb   = Qb + TS;
    __bf16* Vb   = Kb + TS;
    __bf16* Ab   = Vb + TS;
    if (ws_size < 9 * TS * sizeof(__bf16)) return;  // insufficient scratch

    const dim3 blk(256);
    const int castGrid = (int)(TS / 4 / 256);   // 16384
    cast_f32_bf16<<<castGrid, blk, 0, stream>>>(hs, hs_b);
    cast_f32_bf16<<<castGrid, blk, 0, stream>>>(Wq, wq_b);
    cast_f32_bf16<<<castGrid, blk, 0, stream>>>(Wk, wk_b);
    cast_f32_bf16<<<castGrid, blk, 0, stream>>>(Wv, wv_b);
    cast_f32_bf16<<<castGrid, blk, 0, stream>>>(Wo, wo_b);

    const dim3 ggrid(32, 32);  // (N/128, M/128)
    gemm_nt<false><<<ggrid, blk, 0, stream>>>(hs_b, wq_b, (void*)Qb);
    gemm_nt<false><<<ggrid, blk, 0, stream>>>(hs_b, wk_b, (void*)Kb);
    gemm_nt<false><<<ggrid, blk, 0, stream>>>(hs_b, wv_b, (void*)Vb);

    const int ropeGrid = (int)(TS / 2 / 256);   // 32768
    rope_inplace<<<ropeGrid, blk, 0, stream>>>(Qb);
    rope_inplace<<<ropeGrid, blk, 0, stream>>>(Kb);

    flash_attn<<<dim3(32, 64), blk, 0, stream>>>(Qb, Kb, Vb, Ab);

    gemm_nt<true><<<ggrid, blk, 0, stream>>>(Ab, wo_b, (void*)out);
}